// Round 3
// baseline (117.399 us; speedup 1.0000x reference)
//
#include <hip/hip_runtime.h>
#include <math.h>

#define CLS   4096      // row length C
#define KSEL  2048u     // k = round(C * 0.5)
#define TPB   256

// LDS layout (bytes), 16B-aligned regions:
//  h0 : u32[2][2052] @     0  (16416)  pass0 hist, 12-bit bins (2048 used), 2 skewed copies
//  h1 : u32[260]     @ 16416  ( 1040)  pass1 hist, 8-bit (bits 19:12)
//  h2 : u32[260]     @ 17456  ( 1040)  pass2 hist, 8-bit (bits 11:4)
//  h3 : u32[64]      @ 18496  (  256)  pass3 hist, 4-bit (bits 3:0, padded to 64)
//  zero region = [0, 18752) = 1172 uint4, cleared during global-load latency
//  s_wt  u32[4] @18752 ; s_bc u32[3] @18768 ; s_fr f32[8] @18784  -> total 18816
//  aliases (after pass0 dead): s_flag u8[4096] @0 ; s_suf u32[256] @8192 (tie path only)

template<int SHIFT, int NBITS, int BPL>
__device__ __forceinline__ void radix_small(const float sc[16], unsigned* hist,
        int lane, unsigned& prefix, unsigned& kr, unsigned& cnt_eq)
{
    const unsigned msk = (1u << NBITS) - 1u;
    #pragma unroll
    for (int i = 0; i < 16; ++i) {
        unsigned u = __float_as_uint(sc[i]);
        if ((u >> (SHIFT + NBITS)) == (prefix >> (SHIFT + NBITS)))
            atomicAdd(&hist[(u >> SHIFT) & msk], 1u);
    }
    __syncthreads();                       // atomics visible to all waves
    // every wave redundantly scans the whole histogram: no LDS round-trips
    unsigned c[BPL];
    if constexpr (BPL == 4) {
        uint4 x = *(const uint4*)&hist[lane * 4];
        c[0] = x.x; c[1] = x.y; c[2] = x.z; c[3] = x.w;
    } else {
        c[0] = hist[lane];
    }
    unsigned sfx[BPL + 1]; sfx[BPL] = 0;
    #pragma unroll
    for (int j = BPL - 1; j >= 0; --j) sfx[j] = sfx[j + 1] + c[j];
    const unsigned tot = sfx[0];
    unsigned s = tot;
    #pragma unroll
    for (int off = 1; off < 64; off <<= 1) {
        unsigned t = __shfl_down(s, off);
        if (lane + off < 64) s += t;
    }
    const unsigned Sx = s - tot;           // count in bins strictly above this lane's bins
    const bool has = (Sx < kr) && (kr <= Sx + tot);
    unsigned bin = 0, below = 0, ceq = 0;
    if (has) {
        #pragma unroll
        for (int j = 0; j < BPL; ++j)
            if (Sx + sfx[j] >= kr && Sx + sfx[j + 1] < kr) {
                bin = (unsigned)(lane * BPL + j);
                below = Sx + sfx[j + 1];
                ceq = c[j];
            }
    }
    unsigned long long m = __ballot(has);  // exactly one lane set
    int src = (int)__builtin_ctzll(m);
    bin = __shfl(bin, src); below = __shfl(below, src); ceq = __shfl(ceq, src);
    prefix |= bin << SHIFT;
    kr -= below;
    cnt_eq = ceq;
}

__global__ __launch_bounds__(TPB, 8) void proxy_gate_kernel(
    const float* __restrict__ token,
    const float* __restrict__ proxy,
    float* __restrict__ out)
{
    __shared__ __align__(16) unsigned char lds[18816];
    unsigned* h0   = (unsigned*)(lds);
    unsigned* h1   = (unsigned*)(lds + 16416);
    unsigned* h2   = (unsigned*)(lds + 17456);
    unsigned* h3   = (unsigned*)(lds + 18496);
    unsigned* s_wt = (unsigned*)(lds + 18752);
    unsigned* s_bc = (unsigned*)(lds + 18768);
    float*    s_fr = (float*)   (lds + 18784);
    unsigned char* s_flag = lds;                    // alias: h0 dead after pass0
    unsigned*      s_suf  = (unsigned*)(lds + 8192);

    const int tid  = threadIdx.x;
    const int lane = tid & 63;
    const int wv   = tid >> 6;
    const size_t base = (size_t)blockIdx.x * CLS;
    const float4* t4 = (const float4*)(token + base);
    const float4* p4 = (const float4*)(proxy + base);
    float4* o4 = (float4*)(out + base);

    // ---- issue all global loads, zero LDS under their latency ----
    float4 tv[4], pv[4];
    #pragma unroll
    for (int i = 0; i < 4; ++i) { tv[i] = t4[i*TPB + tid]; pv[i] = p4[i*TPB + tid]; }
    {
        uint4 z = make_uint4(0u, 0u, 0u, 0u);
        uint4* zp = (uint4*)lds;
        #pragma unroll
        for (int m = 0; m < 5; ++m) { int idx = m*TPB + tid; if (idx < 1172) zp[idx] = z; }
    }

    float tok[16], sc[16];
    float sum = 0.f, sumsq = 0.f;
    #pragma unroll
    for (int i = 0; i < 4; ++i) {
        float a;
        a = fabsf(tv[i].x*pv[i].x); tok[i*4+0]=tv[i].x; sc[i*4+0]=a; sum+=a; sumsq+=a*a;
        a = fabsf(tv[i].y*pv[i].y); tok[i*4+1]=tv[i].y; sc[i*4+1]=a; sum+=a; sumsq+=a*a;
        a = fabsf(tv[i].z*pv[i].z); tok[i*4+2]=tv[i].z; sc[i*4+2]=a; sum+=a; sumsq+=a*a;
        a = fabsf(tv[i].w*pv[i].w); tok[i*4+3]=tv[i].w; sc[i*4+3]=a; sum+=a; sumsq+=a*a;
    }
    __syncthreads();                                 // B0: zeroing complete

    // ---- pass 0 atomics (12-bit bins) + stats reduce under atomic latency ----
    {
        unsigned* h0c = h0 + (((tid >> 2) & 1) ? 2052 : 0);
        #pragma unroll
        for (int i = 0; i < 16; ++i)
            atomicAdd(&h0c[__float_as_uint(sc[i]) >> 20], 1u);
    }
    #pragma unroll
    for (int off = 32; off > 0; off >>= 1) {
        sum   += __shfl_xor(sum, off);
        sumsq += __shfl_xor(sumsq, off);
    }
    if (lane == 0) { s_fr[wv] = sum; s_fr[4+wv] = sumsq; }
    __syncthreads();                                 // B1: atomics + stats visible

    const float tot_s = s_fr[0]+s_fr[1]+s_fr[2]+s_fr[3];
    const float tot_q = s_fr[4]+s_fr[5]+s_fr[6]+s_fr[7];
    const float mu = tot_s * (1.0f/CLS);
    float var = (tot_q - tot_s*mu) * (1.0f/(CLS-1));
    var = fmaxf(var, 0.0f);
    const float inv_sigma = 1.0f / fmaxf(sqrtf(var), 1e-6f);

    // ---- pass 0 scan: 2048 bins, thread tid owns bins [8t, 8t+8) ----
    unsigned kr = KSEL, prefix = 0, cnt_eq = 0;
    {
        const int bo = tid * 8;
        uint4 x0 = *(const uint4*)&h0[bo];
        uint4 x1 = *(const uint4*)&h0[bo + 4];
        uint4 y0 = *(const uint4*)&h0[2052 + bo];
        uint4 y1 = *(const uint4*)&h0[2052 + bo + 4];
        unsigned c[8] = { x0.x+y0.x, x0.y+y0.y, x0.z+y0.z, x0.w+y0.w,
                          x1.x+y1.x, x1.y+y1.y, x1.z+y1.z, x1.w+y1.w };
        unsigned sfx[9]; sfx[8] = 0;
        #pragma unroll
        for (int j = 7; j >= 0; --j) sfx[j] = sfx[j+1] + c[j];
        const unsigned tot = sfx[0];
        unsigned s = tot;
        #pragma unroll
        for (int off = 1; off < 64; off <<= 1) {
            unsigned t = __shfl_down(s, off);
            if (lane + off < 64) s += t;
        }
        if (lane == 0) s_wt[wv] = s;
        __syncthreads();                             // B2
        unsigned addhi = 0;
        #pragma unroll
        for (int w2 = 0; w2 < 4; ++w2) if (w2 > wv) addhi += s_wt[w2];
        const unsigned Sx = (s - tot) + addhi;       // bins strictly above this thread's
        if (Sx < kr && kr <= Sx + tot) {             // unique thread
            #pragma unroll
            for (int j = 0; j < 8; ++j)
                if (Sx + sfx[j] >= kr && Sx + sfx[j+1] < kr) {
                    s_bc[0] = (unsigned)(bo + j);
                    s_bc[1] = Sx + sfx[j+1];
                    s_bc[2] = c[j];
                }
        }
        __syncthreads();                             // B3
        prefix = s_bc[0] << 20;
        kr    -= s_bc[1];
        cnt_eq = s_bc[2];
    }

    // ---- passes 1-3 on ~cnt_eq candidates, 1 barrier each ----
    radix_small<12, 8, 4>(sc, h1, lane, prefix, kr, cnt_eq);
    radix_small< 4, 8, 4>(sc, h2, lane, prefix, kr, cnt_eq);
    radix_small< 0, 4, 1>(sc, h3, lane, prefix, kr, cnt_eq);

    const float thr = __uint_as_float(prefix);
    const bool tie_rare = (cnt_eq != kr);            // block-uniform

    if (tie_rare) {
        // rank equal-valued elements by global index; first kr of them get hard mask
        #pragma unroll
        for (int i = 0; i < 4; ++i) {
            #pragma unroll
            for (int c2 = 0; c2 < 4; ++c2)
                s_flag[i*1024 + tid*4 + c2] = (sc[i*4+c2] == thr) ? 1 : 0;
        }
        __syncthreads();
        unsigned lc = 0;
        unsigned char mf[16];
        #pragma unroll
        for (int m = 0; m < 16; ++m) { mf[m] = s_flag[tid*16 + m]; lc += mf[m]; }
        s_suf[tid] = lc;
        __syncthreads();
        #pragma unroll
        for (int off = 1; off < 256; off <<= 1) {    // inclusive forward scan
            unsigned w = s_suf[tid] + ((tid >= off) ? s_suf[tid - off] : 0u);
            __syncthreads();
            s_suf[tid] = w;
            __syncthreads();
        }
        unsigned r = s_suf[tid] - lc;                // exclusive prefix (index order)
        #pragma unroll
        for (int m = 0; m < 16; ++m) {
            if (mf[m]) { s_flag[tid*16 + m] = (r < kr) ? 2 : 0; ++r; }
        }
        __syncthreads();
    }

    // ---- gate + store (registers still hold tok/sc) ----
    #pragma unroll
    for (int i = 0; i < 4; ++i) {
        float res[4];
        #pragma unroll
        for (int c2 = 0; c2 < 4; ++c2) {
            const float s = sc[i*4+c2];
            const float z = (s - mu) * inv_sigma;
            const float soft = 1.0f / (1.0f + __expf(-z));
            bool hard;
            if (tie_rare)
                hard = (s > thr) || ((s == thr) && (s_flag[i*1024 + tid*4 + c2] == 2));
            else
                hard = (s >= thr);
            res[c2] = tok[i*4+c2] * (hard ? 1.0f : soft);
        }
        o4[i*TPB + tid] = make_float4(res[0], res[1], res[2], res[3]);
    }
}

extern "C" void kernel_launch(void* const* d_in, const int* in_sizes, int n_in,
                              void* d_out, int out_size, void* d_ws, size_t ws_size,
                              hipStream_t stream) {
    const float* token = (const float*)d_in[0];
    const float* proxy = (const float*)d_in[1];
    float* outp = (float*)d_out;
    const int B = in_sizes[0] / CLS;
    hipLaunchKernelGGL(proxy_gate_kernel, dim3(B), dim3(TPB), 0, stream,
                       token, proxy, outp);
}

// Round 5
// 70.318 us; speedup vs baseline: 1.6695x; 1.6695x over previous
//
#include <hip/hip_runtime.h>
#include <math.h>

#define CLS   4096      // row length C
#define KSEL  2048u     // k = round(C * 0.5)
#define TPB   256

typedef float f32x4 __attribute__((ext_vector_type(4)));   // native vec for nontemporal store

// LDS layout (bytes), 16B-aligned regions:
//  h0 : u32[2][2052] @     0  (16416)  pass0 hist, 12-bit bins (2048 used), 2 skewed copies
//  h1 : u32[260]     @ 16416  ( 1040)  pass1 hist, 8-bit (bits 19:12)
//  h2 : u32[260]     @ 17456  ( 1040)  pass2 hist, 8-bit (bits 11:4)
//  h3 : u32[64]      @ 18496  (  256)  pass3 hist, 4-bit (bits 3:0, padded to 64)
//  zero region = [0, 18752) = 1172 uint4, cleared during global-load latency
//  s_wt  u32[4] @18752 ; s_bc u32[3] @18768 ; s_fr f32[8] @18784  -> total 18816
//  aliases (after pass0 dead): s_flag u8[4096] @0 ; s_suf u32[256] @8192 (tie path only)

template<int SHIFT, int NBITS, int BPL>
__device__ __forceinline__ void radix_small(const float sc[16], unsigned* hist,
        int lane, unsigned& prefix, unsigned& kr, unsigned& cnt_eq)
{
    const unsigned msk = (1u << NBITS) - 1u;
    #pragma unroll
    for (int i = 0; i < 16; ++i) {
        unsigned u = __float_as_uint(sc[i]);
        if ((u >> (SHIFT + NBITS)) == (prefix >> (SHIFT + NBITS)))
            atomicAdd(&hist[(u >> SHIFT) & msk], 1u);
    }
    __syncthreads();                       // atomics visible to all waves
    // every wave redundantly scans the whole histogram: no LDS round-trips
    unsigned c[BPL];
    if constexpr (BPL == 4) {
        uint4 x = *(const uint4*)&hist[lane * 4];
        c[0] = x.x; c[1] = x.y; c[2] = x.z; c[3] = x.w;
    } else {
        c[0] = hist[lane];
    }
    unsigned sfx[BPL + 1]; sfx[BPL] = 0;
    #pragma unroll
    for (int j = BPL - 1; j >= 0; --j) sfx[j] = sfx[j + 1] + c[j];
    const unsigned tot = sfx[0];
    unsigned s = tot;
    #pragma unroll
    for (int off = 1; off < 64; off <<= 1) {
        unsigned t = __shfl_down(s, off);
        if (lane + off < 64) s += t;
    }
    const unsigned Sx = s - tot;           // count in bins strictly above this lane's bins
    const bool has = (Sx < kr) && (kr <= Sx + tot);
    unsigned bin = 0, below = 0, ceq = 0;
    if (has) {
        #pragma unroll
        for (int j = 0; j < BPL; ++j)
            if (Sx + sfx[j] >= kr && Sx + sfx[j + 1] < kr) {
                bin = (unsigned)(lane * BPL + j);
                below = Sx + sfx[j + 1];
                ceq = c[j];
            }
    }
    unsigned long long m = __ballot(has);  // exactly one lane set
    int src = (int)__builtin_ctzll(m);
    bin = __shfl(bin, src); below = __shfl(below, src); ceq = __shfl(ceq, src);
    prefix |= bin << SHIFT;
    kr -= below;
    cnt_eq = ceq;
}

__global__ __launch_bounds__(TPB) void proxy_gate_kernel(
    const float* __restrict__ token,
    const float* __restrict__ proxy,
    float* __restrict__ out)
{
    __shared__ __align__(16) unsigned char lds[18816];
    unsigned* h0   = (unsigned*)(lds);
    unsigned* h1   = (unsigned*)(lds + 16416);
    unsigned* h2   = (unsigned*)(lds + 17456);
    unsigned* h3   = (unsigned*)(lds + 18496);
    unsigned* s_wt = (unsigned*)(lds + 18752);
    unsigned* s_bc = (unsigned*)(lds + 18768);
    float*    s_fr = (float*)   (lds + 18784);
    unsigned char* s_flag = lds;                    // alias: h0 dead after pass0
    unsigned*      s_suf  = (unsigned*)(lds + 8192);

    const int tid  = threadIdx.x;
    const int lane = tid & 63;
    const int wv   = tid >> 6;
    const size_t base = (size_t)blockIdx.x * CLS;
    const float4* t4 = (const float4*)(token + base);
    const float4* p4 = (const float4*)(proxy + base);
    f32x4* o4 = (f32x4*)(out + base);

    // ---- issue all global loads, zero LDS under their latency ----
    float4 tv[4], pv[4];
    #pragma unroll
    for (int i = 0; i < 4; ++i) { tv[i] = t4[i*TPB + tid]; pv[i] = p4[i*TPB + tid]; }
    {
        uint4 z = make_uint4(0u, 0u, 0u, 0u);
        uint4* zp = (uint4*)lds;
        #pragma unroll
        for (int m = 0; m < 5; ++m) { int idx = m*TPB + tid; if (idx < 1172) zp[idx] = z; }
    }

    float tok[16], sc[16];
    float sum = 0.f, sumsq = 0.f;
    #pragma unroll
    for (int i = 0; i < 4; ++i) {
        float a;
        a = fabsf(tv[i].x*pv[i].x); tok[i*4+0]=tv[i].x; sc[i*4+0]=a; sum+=a; sumsq+=a*a;
        a = fabsf(tv[i].y*pv[i].y); tok[i*4+1]=tv[i].y; sc[i*4+1]=a; sum+=a; sumsq+=a*a;
        a = fabsf(tv[i].z*pv[i].z); tok[i*4+2]=tv[i].z; sc[i*4+2]=a; sum+=a; sumsq+=a*a;
        a = fabsf(tv[i].w*pv[i].w); tok[i*4+3]=tv[i].w; sc[i*4+3]=a; sum+=a; sumsq+=a*a;
    }
    __syncthreads();                                 // B0: zeroing complete

    // ---- pass 0 atomics (12-bit bins) + stats reduce under atomic latency ----
    {
        unsigned* h0c = h0 + (((tid >> 2) & 1) ? 2052 : 0);
        #pragma unroll
        for (int i = 0; i < 16; ++i)
            atomicAdd(&h0c[__float_as_uint(sc[i]) >> 20], 1u);
    }
    #pragma unroll
    for (int off = 32; off > 0; off >>= 1) {
        sum   += __shfl_xor(sum, off);
        sumsq += __shfl_xor(sumsq, off);
    }
    if (lane == 0) { s_fr[wv] = sum; s_fr[4+wv] = sumsq; }
    __syncthreads();                                 // B1: atomics + stats visible

    const float tot_s = s_fr[0]+s_fr[1]+s_fr[2]+s_fr[3];
    const float tot_q = s_fr[4]+s_fr[5]+s_fr[6]+s_fr[7];
    const float mu = tot_s * (1.0f/CLS);
    float var = (tot_q - tot_s*mu) * (1.0f/(CLS-1));
    var = fmaxf(var, 0.0f);
    const float inv_sigma = 1.0f / fmaxf(sqrtf(var), 1e-6f);

    // ---- pass 0 scan: 2048 bins, thread tid owns bins [8t, 8t+8) ----
    unsigned kr = KSEL, prefix = 0, cnt_eq = 0;
    {
        const int bo = tid * 8;
        uint4 x0 = *(const uint4*)&h0[bo];
        uint4 x1 = *(const uint4*)&h0[bo + 4];
        uint4 y0 = *(const uint4*)&h0[2052 + bo];
        uint4 y1 = *(const uint4*)&h0[2052 + bo + 4];
        unsigned c[8] = { x0.x+y0.x, x0.y+y0.y, x0.z+y0.z, x0.w+y0.w,
                          x1.x+y1.x, x1.y+y1.y, x1.z+y1.z, x1.w+y1.w };
        unsigned sfx[9]; sfx[8] = 0;
        #pragma unroll
        for (int j = 7; j >= 0; --j) sfx[j] = sfx[j+1] + c[j];
        const unsigned tot = sfx[0];
        unsigned s = tot;
        #pragma unroll
        for (int off = 1; off < 64; off <<= 1) {
            unsigned t = __shfl_down(s, off);
            if (lane + off < 64) s += t;
        }
        if (lane == 0) s_wt[wv] = s;
        __syncthreads();                             // B2
        unsigned addhi = 0;
        #pragma unroll
        for (int w2 = 0; w2 < 4; ++w2) if (w2 > wv) addhi += s_wt[w2];
        const unsigned Sx = (s - tot) + addhi;       // bins strictly above this thread's
        if (Sx < kr && kr <= Sx + tot) {             // unique thread
            #pragma unroll
            for (int j = 0; j < 8; ++j)
                if (Sx + sfx[j] >= kr && Sx + sfx[j+1] < kr) {
                    s_bc[0] = (unsigned)(bo + j);
                    s_bc[1] = Sx + sfx[j+1];
                    s_bc[2] = c[j];
                }
        }
        __syncthreads();                             // B3
        prefix = s_bc[0] << 20;
        kr    -= s_bc[1];
        cnt_eq = s_bc[2];
    }

    // ---- passes 1-3 on ~cnt_eq candidates, 1 barrier each ----
    radix_small<12, 8, 4>(sc, h1, lane, prefix, kr, cnt_eq);
    radix_small< 4, 8, 4>(sc, h2, lane, prefix, kr, cnt_eq);
    radix_small< 0, 4, 1>(sc, h3, lane, prefix, kr, cnt_eq);

    const float thr = __uint_as_float(prefix);
    const bool tie_rare = (cnt_eq != kr);            // block-uniform

    if (tie_rare) {
        // rank equal-valued elements by global index; first kr of them get hard mask
        #pragma unroll
        for (int i = 0; i < 4; ++i) {
            #pragma unroll
            for (int c2 = 0; c2 < 4; ++c2)
                s_flag[i*1024 + tid*4 + c2] = (sc[i*4+c2] == thr) ? 1 : 0;
        }
        __syncthreads();
        unsigned lc = 0;
        unsigned char mf[16];
        #pragma unroll
        for (int m = 0; m < 16; ++m) { mf[m] = s_flag[tid*16 + m]; lc += mf[m]; }
        s_suf[tid] = lc;
        __syncthreads();
        #pragma unroll
        for (int off = 1; off < 256; off <<= 1) {    // inclusive forward scan
            unsigned w = s_suf[tid] + ((tid >= off) ? s_suf[tid - off] : 0u);
            __syncthreads();
            s_suf[tid] = w;
            __syncthreads();
        }
        unsigned r = s_suf[tid] - lc;                // exclusive prefix (index order)
        #pragma unroll
        for (int m = 0; m < 16; ++m) {
            if (mf[m]) { s_flag[tid*16 + m] = (r < kr) ? 2 : 0; ++r; }
        }
        __syncthreads();
    }

    // ---- gate + store (registers still hold tok/sc); nontemporal: don't evict
    //      the input stream from L3 (output is never re-read by this kernel) ----
    #pragma unroll
    for (int i = 0; i < 4; ++i) {
        float res[4];
        #pragma unroll
        for (int c2 = 0; c2 < 4; ++c2) {
            const float s = sc[i*4+c2];
            const float z = (s - mu) * inv_sigma;
            const float soft = 1.0f / (1.0f + __expf(-z));
            bool hard;
            if (tie_rare)
                hard = (s > thr) || ((s == thr) && (s_flag[i*1024 + tid*4 + c2] == 2));
            else
                hard = (s >= thr);
            res[c2] = tok[i*4+c2] * (hard ? 1.0f : soft);
        }
        f32x4 rv = { res[0], res[1], res[2], res[3] };
        __builtin_nontemporal_store(rv, &o4[i*TPB + tid]);
    }
}

extern "C" void kernel_launch(void* const* d_in, const int* in_sizes, int n_in,
                              void* d_out, int out_size, void* d_ws, size_t ws_size,
                              hipStream_t stream) {
    const float* token = (const float*)d_in[0];
    const float* proxy = (const float*)d_in[1];
    float* outp = (float*)d_out;
    const int B = in_sizes[0] / CLS;
    hipLaunchKernelGGL(proxy_gate_kernel, dim3(B), dim3(TPB), 0, stream,
                       token, proxy, outp);
}